// Round 1
// baseline (800.130 us; speedup 1.0000x reference)
//
#include <hip/hip_runtime.h>
#include <math.h>

#define NL 16
#define NF 2
#define LOG2_T 19
#define TSZ (1u << LOG2_T)
#define WIDTH 64
#define OUTW 16

__global__ __launch_bounds__(256) void ngp_fused_kernel(
    const float* __restrict__ xyz,
    const float* __restrict__ bb,
    const float* __restrict__ table,
    const float* __restrict__ W1, const float* __restrict__ b1,
    const float* __restrict__ W2, const float* __restrict__ b2,
    const float* __restrict__ W3, const float* __restrict__ b3,
    const int* __restrict__ resolutions,
    float* __restrict__ out, int n)
{
    const int idx = blockIdx.x * blockDim.x + threadIdx.x;
    if (idx >= n) return;

    // normalize coords to [0,1]^3
    const float bx0 = bb[0], by0 = bb[1], bz0 = bb[2];
    const float bx1 = bb[3], by1 = bb[4], bz1 = bb[5];
    const float x = (xyz[idx * 3 + 0] - bx0) / (bx1 - bx0);
    const float y = (xyz[idx * 3 + 1] - by0) / (by1 - by0);
    const float z = (xyz[idx * 3 + 2] - bz0) / (bz1 - bz0);

    // ---- hash-grid encode: feats[32] ----
    float feats[NL * NF];
#pragma unroll
    for (int l = 0; l < NL; ++l) {
        const float res = (float)resolutions[l];
        const float xs = x * res, ys = y * res, zs = z * res;
        const float xf = floorf(xs), yf = floorf(ys), zf = floorf(zs);
        const float fx = xs - xf, fy = ys - yf, fz = zs - zf;
        const unsigned cx = (unsigned)(int)xf;
        const unsigned cy = (unsigned)(int)yf;
        const unsigned cz = (unsigned)(int)zf;
        const float* tl = table + (size_t)l * (size_t)TSZ * NF;
        float a0 = 0.f, a1 = 0.f;
#pragma unroll
        for (int c = 0; c < 8; ++c) {
            const unsigned ox = (c >> 2) & 1, oy = (c >> 1) & 1, oz = c & 1;
            unsigned h = (cx + ox) ^ ((cy + oy) * 2654435761u) ^ ((cz + oz) * 805459861u);
            h &= (TSZ - 1u);
            const float2 f = *reinterpret_cast<const float2*>(tl + (size_t)h * 2u);
            const float w = (ox ? fx : 1.f - fx) * (oy ? fy : 1.f - fy) * (oz ? fz : 1.f - fz);
            a0 = fmaf(w, f.x, a0);
            a1 = fmaf(w, f.y, a1);
        }
        feats[2 * l]     = a0;
        feats[2 * l + 1] = a1;
    }

    // ---- layer 1: h1 = relu(feats @ W1 + b1), W1 is [32][64] row-major ----
    float h1[WIDTH];
#pragma unroll
    for (int j = 0; j < WIDTH; ++j) h1[j] = b1[j];
#pragma unroll
    for (int i = 0; i < NL * NF; ++i) {
        const float v = feats[i];
#pragma unroll
        for (int j = 0; j < WIDTH; ++j) h1[j] = fmaf(v, W1[i * WIDTH + j], h1[j]);
    }
#pragma unroll
    for (int j = 0; j < WIDTH; ++j) h1[j] = fmaxf(h1[j], 0.f);

    // ---- layer 2 + layer 3 column 0 fused:
    // z0 = b3[0] + sum_j relu(b2[j] + sum_i h1[i]*W2[i][j]) * W3[j][0]
    float z0 = b3[0];
#pragma unroll
    for (int j = 0; j < WIDTH; ++j) {
        float acc = b2[j];
#pragma unroll
        for (int i = 0; i < WIDTH; ++i) acc = fmaf(h1[i], W2[i * WIDTH + j], acc);
        acc = fmaxf(acc, 0.f);
        z0 = fmaf(acc, W3[j * OUTW + 0], z0);
    }

    // softplus, numerically stable
    const float d = (z0 > 0.f) ? (z0 + log1pf(expf(-z0))) : log1pf(expf(z0));
    out[idx] = d;
}

extern "C" void kernel_launch(void* const* d_in, const int* in_sizes, int n_in,
                              void* d_out, int out_size, void* d_ws, size_t ws_size,
                              hipStream_t stream) {
    const float* xyz   = (const float*)d_in[0];
    const float* bb    = (const float*)d_in[1];
    const float* table = (const float*)d_in[2];
    const float* W1    = (const float*)d_in[3];
    const float* b1    = (const float*)d_in[4];
    const float* W2    = (const float*)d_in[5];
    const float* b2    = (const float*)d_in[6];
    const float* W3    = (const float*)d_in[7];
    const float* b3    = (const float*)d_in[8];
    const int*   res   = (const int*)d_in[9];
    float* out = (float*)d_out;
    const int n = out_size;

    const int block = 256;
    const int grid = (n + block - 1) / block;
    ngp_fused_kernel<<<grid, block, 0, stream>>>(xyz, bb, table, W1, b1, W2, b2,
                                                 W3, b3, res, out, n);
}

// Round 2
// 697.592 us; speedup vs baseline: 1.1470x; 1.1470x over previous
//
#include <hip/hip_runtime.h>
#include <math.h>

#define NL 16
#define NF 2
#define LOG2_T 19
#define TSZ (1u << LOG2_T)
#define WIDTH 64
#define OUTW 16

// ---------------- Kernel 1: hash-grid encode, level-major ----------------
// grid = (ceil(n/256), 16). blockIdx.y = level. Blocks of the same level are
// dispatched contiguously -> concurrently-resident blocks share one level's
// 4 MB table -> it fits a per-XCD L2.
// Output layout: feats_ws[l][n][2] (float2 per point/level), fully coalesced.
__global__ __launch_bounds__(256) void ngp_encode_kernel(
    const float* __restrict__ xyz,
    const float* __restrict__ bb,
    const float* __restrict__ table,
    const int* __restrict__ resolutions,
    float2* __restrict__ feats_ws, int n)
{
    const int l = blockIdx.y;
    const int idx = blockIdx.x * blockDim.x + threadIdx.x;
    if (idx >= n) return;

    const float bx0 = bb[0], by0 = bb[1], bz0 = bb[2];
    const float bx1 = bb[3], by1 = bb[4], bz1 = bb[5];
    const float x = (xyz[idx * 3 + 0] - bx0) / (bx1 - bx0);
    const float y = (xyz[idx * 3 + 1] - by0) / (by1 - by0);
    const float z = (xyz[idx * 3 + 2] - bz0) / (bz1 - bz0);

    const float res = (float)resolutions[l];
    const float xs = x * res, ys = y * res, zs = z * res;
    const float xf = floorf(xs), yf = floorf(ys), zf = floorf(zs);
    const float fx = xs - xf, fy = ys - yf, fz = zs - zf;
    const unsigned cx = (unsigned)(int)xf;
    const unsigned cy = (unsigned)(int)yf;
    const unsigned cz = (unsigned)(int)zf;
    const float* tl = table + (size_t)l * (size_t)TSZ * NF;

    float a0 = 0.f, a1 = 0.f;
#pragma unroll
    for (int c = 0; c < 8; ++c) {
        const unsigned ox = (c >> 2) & 1, oy = (c >> 1) & 1, oz = c & 1;
        unsigned h = (cx + ox) ^ ((cy + oy) * 2654435761u) ^ ((cz + oz) * 805459861u);
        h &= (TSZ - 1u);
        const float2 f = *reinterpret_cast<const float2*>(tl + (size_t)h * 2u);
        const float w = (ox ? fx : 1.f - fx) * (oy ? fy : 1.f - fy) * (oz ? fz : 1.f - fz);
        a0 = fmaf(w, f.x, a0);
        a1 = fmaf(w, f.y, a1);
    }
    feats_ws[(size_t)l * (size_t)n + (size_t)idx] = make_float2(a0, a1);
}

// ---------------- Kernel 2: MLP (VALU fp32) ----------------
__global__ __launch_bounds__(256, 2) void ngp_mlp_kernel(
    const float2* __restrict__ feats_ws,
    const float* __restrict__ W1, const float* __restrict__ b1,
    const float* __restrict__ W2, const float* __restrict__ b2,
    const float* __restrict__ W3, const float* __restrict__ b3,
    float* __restrict__ out, int n)
{
    const int idx = blockIdx.x * blockDim.x + threadIdx.x;
    if (idx >= n) return;

    float feats[NL * NF];
#pragma unroll
    for (int l = 0; l < NL; ++l) {
        const float2 v = feats_ws[(size_t)l * (size_t)n + (size_t)idx];
        feats[2 * l]     = v.x;
        feats[2 * l + 1] = v.y;
    }

    // layer 1: h1 = relu(feats @ W1 + b1); W1 is [32][64] row-major
    float h1[WIDTH];
#pragma unroll
    for (int j = 0; j < WIDTH; ++j) h1[j] = b1[j];
#pragma unroll
    for (int i = 0; i < NL * NF; ++i) {
        const float v = feats[i];
#pragma unroll
        for (int j = 0; j < WIDTH; ++j) h1[j] = fmaf(v, W1[i * WIDTH + j], h1[j]);
    }
#pragma unroll
    for (int j = 0; j < WIDTH; ++j) h1[j] = fmaxf(h1[j], 0.f);

    // layer 2 + layer 3 col 0 fused:
    // z0 = b3[0] + sum_j relu(b2[j] + sum_i h1[i]*W2[i][j]) * W3[j][0]
    float z0 = b3[0];
#pragma unroll 4
    for (int j = 0; j < WIDTH; ++j) {
        float acc = b2[j];
#pragma unroll
        for (int i = 0; i < WIDTH; ++i) acc = fmaf(h1[i], W2[i * WIDTH + j], acc);
        acc = fmaxf(acc, 0.f);
        z0 = fmaf(acc, W3[j * OUTW + 0], z0);
    }

    const float d = (z0 > 0.f) ? (z0 + log1pf(expf(-z0))) : log1pf(expf(z0));
    out[idx] = d;
}

// ---------------- Fallback: proven fused kernel (R1) ----------------
__global__ __launch_bounds__(256) void ngp_fused_kernel(
    const float* __restrict__ xyz,
    const float* __restrict__ bb,
    const float* __restrict__ table,
    const float* __restrict__ W1, const float* __restrict__ b1,
    const float* __restrict__ W2, const float* __restrict__ b2,
    const float* __restrict__ W3, const float* __restrict__ b3,
    const int* __restrict__ resolutions,
    float* __restrict__ out, int n)
{
    const int idx = blockIdx.x * blockDim.x + threadIdx.x;
    if (idx >= n) return;

    const float bx0 = bb[0], by0 = bb[1], bz0 = bb[2];
    const float bx1 = bb[3], by1 = bb[4], bz1 = bb[5];
    const float x = (xyz[idx * 3 + 0] - bx0) / (bx1 - bx0);
    const float y = (xyz[idx * 3 + 1] - by0) / (by1 - by0);
    const float z = (xyz[idx * 3 + 2] - bz0) / (bz1 - bz0);

    float feats[NL * NF];
#pragma unroll
    for (int l = 0; l < NL; ++l) {
        const float res = (float)resolutions[l];
        const float xs = x * res, ys = y * res, zs = z * res;
        const float xf = floorf(xs), yf = floorf(ys), zf = floorf(zs);
        const float fx = xs - xf, fy = ys - yf, fz = zs - zf;
        const unsigned cx = (unsigned)(int)xf;
        const unsigned cy = (unsigned)(int)yf;
        const unsigned cz = (unsigned)(int)zf;
        const float* tl = table + (size_t)l * (size_t)TSZ * NF;
        float a0 = 0.f, a1 = 0.f;
#pragma unroll
        for (int c = 0; c < 8; ++c) {
            const unsigned ox = (c >> 2) & 1, oy = (c >> 1) & 1, oz = c & 1;
            unsigned h = (cx + ox) ^ ((cy + oy) * 2654435761u) ^ ((cz + oz) * 805459861u);
            h &= (TSZ - 1u);
            const float2 f = *reinterpret_cast<const float2*>(tl + (size_t)h * 2u);
            const float w = (ox ? fx : 1.f - fx) * (oy ? fy : 1.f - fy) * (oz ? fz : 1.f - fz);
            a0 = fmaf(w, f.x, a0);
            a1 = fmaf(w, f.y, a1);
        }
        feats[2 * l]     = a0;
        feats[2 * l + 1] = a1;
    }

    float h1[WIDTH];
#pragma unroll
    for (int j = 0; j < WIDTH; ++j) h1[j] = b1[j];
#pragma unroll
    for (int i = 0; i < NL * NF; ++i) {
        const float v = feats[i];
#pragma unroll
        for (int j = 0; j < WIDTH; ++j) h1[j] = fmaf(v, W1[i * WIDTH + j], h1[j]);
    }
#pragma unroll
    for (int j = 0; j < WIDTH; ++j) h1[j] = fmaxf(h1[j], 0.f);

    float z0 = b3[0];
#pragma unroll 4
    for (int j = 0; j < WIDTH; ++j) {
        float acc = b2[j];
#pragma unroll
        for (int i = 0; i < WIDTH; ++i) acc = fmaf(h1[i], W2[i * WIDTH + j], acc);
        acc = fmaxf(acc, 0.f);
        z0 = fmaf(acc, W3[j * OUTW + 0], z0);
    }

    const float d = (z0 > 0.f) ? (z0 + log1pf(expf(-z0))) : log1pf(expf(z0));
    out[idx] = d;
}

extern "C" void kernel_launch(void* const* d_in, const int* in_sizes, int n_in,
                              void* d_out, int out_size, void* d_ws, size_t ws_size,
                              hipStream_t stream) {
    const float* xyz   = (const float*)d_in[0];
    const float* bb    = (const float*)d_in[1];
    const float* table = (const float*)d_in[2];
    const float* W1    = (const float*)d_in[3];
    const float* b1    = (const float*)d_in[4];
    const float* W2    = (const float*)d_in[5];
    const float* b2    = (const float*)d_in[6];
    const float* W3    = (const float*)d_in[7];
    const float* b3    = (const float*)d_in[8];
    const int*   res   = (const int*)d_in[9];
    float* out = (float*)d_out;
    const int n = out_size;

    const int block = 256;
    const int pblocks = (n + block - 1) / block;
    const size_t need = (size_t)NL * (size_t)n * sizeof(float2);

    if (ws_size >= need) {
        float2* feats_ws = (float2*)d_ws;
        dim3 grid(pblocks, NL);
        ngp_encode_kernel<<<grid, block, 0, stream>>>(xyz, bb, table, res, feats_ws, n);
        ngp_mlp_kernel<<<pblocks, block, 0, stream>>>(feats_ws, W1, b1, W2, b2, W3, b3, out, n);
    } else {
        ngp_fused_kernel<<<pblocks, block, 0, stream>>>(xyz, bb, table, W1, b1, W2, b2,
                                                        W3, b3, res, out, n);
    }
}

// Round 3
// 583.335 us; speedup vs baseline: 1.3716x; 1.1959x over previous
//
#include <hip/hip_runtime.h>
#include <math.h>

#define NL 16
#define NF 2
#define LOG2_T 19
#define TSZ (1u << LOG2_T)
#define WIDTH 64
#define OUTW 16

typedef short bf16x8 __attribute__((ext_vector_type(8)));
typedef float f32x4 __attribute__((ext_vector_type(4)));

union FragU { uint4 u; bf16x8 v; };

__device__ __forceinline__ unsigned short f2bf(float f) {
    unsigned u = __builtin_bit_cast(unsigned, f);
    unsigned r = u + 0x7fffu + ((u >> 16) & 1u);
    return (unsigned short)(r >> 16);
}

// ---------------- Kernel 0: weight prep (f32 -> bf16, transposed [n][k]) ----
__global__ __launch_bounds__(256) void ngp_prep_kernel(
    const float* __restrict__ W1, const float* __restrict__ W2,
    unsigned short* __restrict__ W1t, unsigned short* __restrict__ W2t)
{
    const int i = blockIdx.x * blockDim.x + threadIdx.x;
    if (i < 32 * 64) {                       // W1t[n][k], n=64, k=32
        const int nn = i >> 5, k = i & 31;
        W1t[i] = f2bf(W1[k * 64 + nn]);
    } else if (i < 32 * 64 + 64 * 64) {      // W2t[n][k], n=64, k=64
        const int j = i - 32 * 64;
        const int nn = j >> 6, k = j & 63;
        W2t[j] = f2bf(W2[k * 64 + nn]);
    }
}

// ---------------- Kernel 1: hash-grid encode, level-major, bf16 out --------
// grid = (ceil(n/256), 16), blockIdx.y = level. feats layout: uint fws[l][n],
// low ushort = feature 2l, high ushort = feature 2l+1 (bf16).
__global__ __launch_bounds__(256) void ngp_encode_kernel(
    const float* __restrict__ xyz,
    const float* __restrict__ bb,
    const float* __restrict__ table,
    const int* __restrict__ resolutions,
    unsigned int* __restrict__ fws, int n)
{
    const int l = blockIdx.y;
    const int idx = blockIdx.x * blockDim.x + threadIdx.x;
    if (idx >= n) return;

    const float bx0 = bb[0], by0 = bb[1], bz0 = bb[2];
    const float bx1 = bb[3], by1 = bb[4], bz1 = bb[5];
    const float x = (xyz[idx * 3 + 0] - bx0) / (bx1 - bx0);
    const float y = (xyz[idx * 3 + 1] - by0) / (by1 - by0);
    const float z = (xyz[idx * 3 + 2] - bz0) / (bz1 - bz0);

    const float res = (float)resolutions[l];
    const float xs = x * res, ys = y * res, zs = z * res;
    const float xf = floorf(xs), yf = floorf(ys), zf = floorf(zs);
    const float fx = xs - xf, fy = ys - yf, fz = zs - zf;
    const unsigned cx = (unsigned)(int)xf;
    const unsigned cy = (unsigned)(int)yf;
    const unsigned cz = (unsigned)(int)zf;
    const float* tl = table + (size_t)l * (size_t)TSZ * NF;

    float a0 = 0.f, a1 = 0.f;
#pragma unroll
    for (int c = 0; c < 8; ++c) {
        const unsigned ox = (c >> 2) & 1, oy = (c >> 1) & 1, oz = c & 1;
        unsigned h = (cx + ox) ^ ((cy + oy) * 2654435761u) ^ ((cz + oz) * 805459861u);
        h &= (TSZ - 1u);
        const float2 f = *reinterpret_cast<const float2*>(tl + (size_t)h * 2u);
        const float w = (ox ? fx : 1.f - fx) * (oy ? fy : 1.f - fy) * (oz ? fz : 1.f - fz);
        a0 = fmaf(w, f.x, a0);
        a1 = fmaf(w, f.y, a1);
    }
    fws[(size_t)l * (size_t)n + (size_t)idx] =
        ((unsigned)f2bf(a1) << 16) | (unsigned)f2bf(a0);
}

// ---------------- Kernel 2: MFMA MLP -----------------------------------
// One wave = 64 points. L1: 16x mfma 16x16x32 bf16; h1 -> LDS (bf16,
// XOR-swizzled); L2: 32x mfma; L3 col-0 dot + shfl reduce. No barriers
// (per-wave LDS slice).
__global__ __launch_bounds__(256) void ngp_mfma_mlp_kernel(
    const unsigned int* __restrict__ fws,
    const unsigned short* __restrict__ W1t, const float* __restrict__ b1,
    const unsigned short* __restrict__ W2t, const float* __restrict__ b2,
    const float* __restrict__ W3, const float* __restrict__ b3,
    float* __restrict__ out, int n)
{
    __shared__ unsigned short h1_lds[4][64 * WIDTH];  // 4 waves x 8KB
    const int lane = threadIdx.x & 63;
    const int wid  = threadIdx.x >> 6;
    const int wbase = (blockIdx.x * 4 + wid) * 64;
    if (wbase >= n) return;

    unsigned short* myLds = h1_lds[wid];
    const int col = lane & 15;       // m (A/D row) | n (B/D col)
    const int q   = lane >> 4;       // k-group

    // ---- layer 1 ----
    FragU B1[4];
#pragma unroll
    for (int nt = 0; nt < 4; ++nt)
        B1[nt].u = *reinterpret_cast<const uint4*>(W1t + ((nt * 16 + col) * 32 + q * 8));
    float b1v[4];
#pragma unroll
    for (int nt = 0; nt < 4; ++nt) b1v[nt] = b1[nt * 16 + col];

#pragma unroll
    for (int mt = 0; mt < 4; ++mt) {
        int p = wbase + mt * 16 + col;
        int pc = p < n ? p : n - 1;
        FragU A;
        A.u.x = fws[(size_t)(q * 4 + 0) * (size_t)n + pc];
        A.u.y = fws[(size_t)(q * 4 + 1) * (size_t)n + pc];
        A.u.z = fws[(size_t)(q * 4 + 2) * (size_t)n + pc];
        A.u.w = fws[(size_t)(q * 4 + 3) * (size_t)n + pc];

        f32x4 acc[4] = {f32x4{0.f,0.f,0.f,0.f}, f32x4{0.f,0.f,0.f,0.f},
                        f32x4{0.f,0.f,0.f,0.f}, f32x4{0.f,0.f,0.f,0.f}};
#pragma unroll
        for (int nt = 0; nt < 4; ++nt)
            acc[nt] = __builtin_amdgcn_mfma_f32_16x16x32_bf16(A.v, B1[nt].v, acc[nt], 0, 0, 0);

#pragma unroll
        for (int nt = 0; nt < 4; ++nt) {
#pragma unroll
            for (int r = 0; r < 4; ++r) {
                float v = acc[nt][r] + b1v[nt];
                v = fmaxf(v, 0.f);
                const int pl = mt * 16 + q * 4 + r;      // local point (D row)
                const int f  = nt * 16 + col;            // feature (D col)
                myLds[pl * WIDTH + (f ^ ((pl & 7) << 3))] = f2bf(v);
            }
        }
    }

    // ---- layer 2 + layer 3 (col 0) ----
    FragU B2[4][2];
#pragma unroll
    for (int nt = 0; nt < 4; ++nt)
#pragma unroll
        for (int kt = 0; kt < 2; ++kt)
            B2[nt][kt].u = *reinterpret_cast<const uint4*>(
                W2t + ((nt * 16 + col) * 64 + kt * 32 + q * 8));
    float b2v[4], w3v[4];
#pragma unroll
    for (int nt = 0; nt < 4; ++nt) {
        b2v[nt] = b2[nt * 16 + col];
        w3v[nt] = W3[(nt * 16 + col) * OUTW];
    }
    const float bias3 = b3[0];

#pragma unroll
    for (int mt = 0; mt < 4; ++mt) {
        f32x4 acc[4] = {f32x4{0.f,0.f,0.f,0.f}, f32x4{0.f,0.f,0.f,0.f},
                        f32x4{0.f,0.f,0.f,0.f}, f32x4{0.f,0.f,0.f,0.f}};
#pragma unroll
        for (int kt = 0; kt < 2; ++kt) {
            const int pl = mt * 16 + col;                // A row
            const int f0 = kt * 32 + q * 8;              // k base
            FragU A2;
            A2.u = *reinterpret_cast<const uint4*>(&myLds[pl * WIDTH + (f0 ^ ((pl & 7) << 3))]);
#pragma unroll
            for (int nt = 0; nt < 4; ++nt)
                acc[nt] = __builtin_amdgcn_mfma_f32_16x16x32_bf16(A2.v, B2[nt][kt].v, acc[nt], 0, 0, 0);
        }
        float sp0 = 0.f, sp1 = 0.f, sp2 = 0.f, sp3 = 0.f;
#pragma unroll
        for (int r = 0; r < 4; ++r) {
            float s = 0.f;
#pragma unroll
            for (int nt = 0; nt < 4; ++nt) {
                const float h = fmaxf(acc[nt][r] + b2v[nt], 0.f);
                s = fmaf(h, w3v[nt], s);
            }
            s += __shfl_xor(s, 1);
            s += __shfl_xor(s, 2);
            s += __shfl_xor(s, 4);
            s += __shfl_xor(s, 8);
            const float z0 = s + bias3;
            const float d = (z0 > 0.f) ? (z0 + log1pf(expf(-z0))) : log1pf(expf(z0));
            if (r == 0) sp0 = d; else if (r == 1) sp1 = d; else if (r == 2) sp2 = d; else sp3 = d;
        }
        if (col < 4) {
            const float selv = (col == 0) ? sp0 : (col == 1) ? sp1 : (col == 2) ? sp2 : sp3;
            const int p = wbase + mt * 16 + q * 4 + col;
            if (p < n) out[p] = selv;
        }
    }
}

// ---------------- Fallback: proven fused kernel (R1) ----------------
__global__ __launch_bounds__(256) void ngp_fused_kernel(
    const float* __restrict__ xyz,
    const float* __restrict__ bb,
    const float* __restrict__ table,
    const float* __restrict__ W1, const float* __restrict__ b1,
    const float* __restrict__ W2, const float* __restrict__ b2,
    const float* __restrict__ W3, const float* __restrict__ b3,
    const int* __restrict__ resolutions,
    float* __restrict__ out, int n)
{
    const int idx = blockIdx.x * blockDim.x + threadIdx.x;
    if (idx >= n) return;

    const float bx0 = bb[0], by0 = bb[1], bz0 = bb[2];
    const float bx1 = bb[3], by1 = bb[4], bz1 = bb[5];
    const float x = (xyz[idx * 3 + 0] - bx0) / (bx1 - bx0);
    const float y = (xyz[idx * 3 + 1] - by0) / (by1 - by0);
    const float z = (xyz[idx * 3 + 2] - bz0) / (bz1 - bz0);

    float feats[NL * NF];
#pragma unroll
    for (int l = 0; l < NL; ++l) {
        const float res = (float)resolutions[l];
        const float xs = x * res, ys = y * res, zs = z * res;
        const float xf = floorf(xs), yf = floorf(ys), zf = floorf(zs);
        const float fx = xs - xf, fy = ys - yf, fz = zs - zf;
        const unsigned cx = (unsigned)(int)xf;
        const unsigned cy = (unsigned)(int)yf;
        const unsigned cz = (unsigned)(int)zf;
        const float* tl = table + (size_t)l * (size_t)TSZ * NF;
        float a0 = 0.f, a1 = 0.f;
#pragma unroll
        for (int c = 0; c < 8; ++c) {
            const unsigned ox = (c >> 2) & 1, oy = (c >> 1) & 1, oz = c & 1;
            unsigned h = (cx + ox) ^ ((cy + oy) * 2654435761u) ^ ((cz + oz) * 805459861u);
            h &= (TSZ - 1u);
            const float2 f = *reinterpret_cast<const float2*>(tl + (size_t)h * 2u);
            const float w = (ox ? fx : 1.f - fx) * (oy ? fy : 1.f - fy) * (oz ? fz : 1.f - fz);
            a0 = fmaf(w, f.x, a0);
            a1 = fmaf(w, f.y, a1);
        }
        feats[2 * l]     = a0;
        feats[2 * l + 1] = a1;
    }

    float h1[WIDTH];
#pragma unroll
    for (int j = 0; j < WIDTH; ++j) h1[j] = b1[j];
#pragma unroll
    for (int i = 0; i < NL * NF; ++i) {
        const float v = feats[i];
#pragma unroll
        for (int j = 0; j < WIDTH; ++j) h1[j] = fmaf(v, W1[i * WIDTH + j], h1[j]);
    }
#pragma unroll
    for (int j = 0; j < WIDTH; ++j) h1[j] = fmaxf(h1[j], 0.f);

    float z0 = b3[0];
#pragma unroll 4
    for (int j = 0; j < WIDTH; ++j) {
        float acc = b2[j];
#pragma unroll
        for (int i = 0; i < WIDTH; ++i) acc = fmaf(h1[i], W2[i * WIDTH + j], acc);
        acc = fmaxf(acc, 0.f);
        z0 = fmaf(acc, W3[j * OUTW + 0], z0);
    }

    const float d = (z0 > 0.f) ? (z0 + log1pf(expf(-z0))) : log1pf(expf(z0));
    out[idx] = d;
}

extern "C" void kernel_launch(void* const* d_in, const int* in_sizes, int n_in,
                              void* d_out, int out_size, void* d_ws, size_t ws_size,
                              hipStream_t stream) {
    const float* xyz   = (const float*)d_in[0];
    const float* bb    = (const float*)d_in[1];
    const float* table = (const float*)d_in[2];
    const float* W1    = (const float*)d_in[3];
    const float* b1    = (const float*)d_in[4];
    const float* W2    = (const float*)d_in[5];
    const float* b2    = (const float*)d_in[6];
    const float* W3    = (const float*)d_in[7];
    const float* b3    = (const float*)d_in[8];
    const int*   res   = (const int*)d_in[9];
    float* out = (float*)d_out;
    const int n = out_size;

    const int block = 256;
    const int pblocks = (n + block - 1) / block;

    const size_t fsz  = (size_t)NL * (size_t)n * sizeof(unsigned int); // bf16x2 feats
    const size_t need = fsz + (32 * 64 + 64 * 64) * sizeof(unsigned short) + 256;

    if (ws_size >= need) {
        unsigned int*   fws = (unsigned int*)d_ws;
        unsigned short* W1t = (unsigned short*)((char*)d_ws + fsz);
        unsigned short* W2t = W1t + 32 * 64;

        ngp_prep_kernel<<<24, 256, 0, stream>>>(W1, W2, W1t, W2t);
        dim3 egrid(pblocks, NL);
        ngp_encode_kernel<<<egrid, block, 0, stream>>>(xyz, bb, table, res, fws, n);
        const int nwaves  = (n + 63) / 64;
        const int mblocks = (nwaves + 3) / 4;
        ngp_mfma_mlp_kernel<<<mblocks, block, 0, stream>>>(fws, W1t, b1, W2t, b2, W3, b3, out, n);
    } else {
        ngp_fused_kernel<<<pblocks, block, 0, stream>>>(xyz, bb, table, W1, b1, W2, b2,
                                                        W3, b3, res, out, n);
    }
}

// Round 4
// 567.495 us; speedup vs baseline: 1.4099x; 1.0279x over previous
//
#include <hip/hip_runtime.h>
#include <math.h>

#define NL 16
#define NF 2
#define LOG2_T 19
#define TSZ (1u << LOG2_T)
#define WIDTH 64
#define OUTW 16

typedef short bf16x8 __attribute__((ext_vector_type(8)));
typedef float f32x4 __attribute__((ext_vector_type(4)));

union FragU { uint4 u; bf16x8 v; };

__device__ __forceinline__ unsigned short f2bf(float f) {
    unsigned u = __builtin_bit_cast(unsigned, f);
    unsigned r = u + 0x7fffu + ((u >> 16) & 1u);
    return (unsigned short)(r >> 16);
}
__device__ __forceinline__ float bflo(unsigned u) {
    return __builtin_bit_cast(float, u << 16);
}
__device__ __forceinline__ float bfhi(unsigned u) {
    return __builtin_bit_cast(float, u & 0xffff0000u);
}

// ---------------- Kernel 0a: table f32 -> packed bf16x2 -------------------
// tb_bf[l*T + h] = (bf16(feat1) << 16) | bf16(feat0)
__global__ __launch_bounds__(256) void ngp_prep_table_kernel(
    const float* __restrict__ table, unsigned int* __restrict__ tb_bf)
{
    const int i = blockIdx.x * blockDim.x + threadIdx.x;   // entry index
    if (i >= NL * (int)TSZ) return;
    const float2 e = *reinterpret_cast<const float2*>(table + (size_t)i * 2u);
    tb_bf[i] = ((unsigned)f2bf(e.y) << 16) | (unsigned)f2bf(e.x);
}

// ---------------- Kernel 0b: weight prep (f32 -> bf16, transposed [n][k]) --
__global__ __launch_bounds__(256) void ngp_prep_w_kernel(
    const float* __restrict__ W1, const float* __restrict__ W2,
    unsigned short* __restrict__ W1t, unsigned short* __restrict__ W2t)
{
    const int i = blockIdx.x * blockDim.x + threadIdx.x;
    if (i < 32 * 64) {                       // W1t[n][k], n=64, k=32
        const int nn = i >> 5, k = i & 31;
        W1t[i] = f2bf(W1[k * 64 + nn]);
    } else if (i < 32 * 64 + 64 * 64) {      // W2t[n][k], n=64, k=64
        const int j = i - 32 * 64;
        const int nn = j >> 6, k = j & 63;
        W2t[j] = f2bf(W2[k * 64 + nn]);
    }
}

// ---------------- Kernel 1: hash-grid encode, level-major, bf16 table ------
// grid = (ceil(n/256), 16), blockIdx.y = level. Output: uint fws[l][n],
// low/high ushort = bf16 features 2l / 2l+1.
// Levels >= 4 are hash-random across >=2MB -> L1 hit ~0 -> use nt loads
// (no L1 allocate). Levels < 4 have small footprints -> cached loads.
__global__ __launch_bounds__(256) void ngp_encode_kernel(
    const float* __restrict__ xyz,
    const float* __restrict__ bb,
    const unsigned int* __restrict__ tb_bf,
    const int* __restrict__ resolutions,
    unsigned int* __restrict__ fws, int n)
{
    const int l = blockIdx.y;
    const int idx = blockIdx.x * blockDim.x + threadIdx.x;
    if (idx >= n) return;

    const float bx0 = bb[0], by0 = bb[1], bz0 = bb[2];
    const float bx1 = bb[3], by1 = bb[4], bz1 = bb[5];
    const float x = (xyz[idx * 3 + 0] - bx0) / (bx1 - bx0);
    const float y = (xyz[idx * 3 + 1] - by0) / (by1 - by0);
    const float z = (xyz[idx * 3 + 2] - bz0) / (bz1 - bz0);

    const float res = (float)resolutions[l];
    const float xs = x * res, ys = y * res, zs = z * res;
    const float xf = floorf(xs), yf = floorf(ys), zf = floorf(zs);
    const float fx = xs - xf, fy = ys - yf, fz = zs - zf;
    const unsigned cx = (unsigned)(int)xf;
    const unsigned cy = (unsigned)(int)yf;
    const unsigned cz = (unsigned)(int)zf;
    const unsigned int* tl = tb_bf + (size_t)l * (size_t)TSZ;

    unsigned hh[8];
#pragma unroll
    for (int c = 0; c < 8; ++c) {
        const unsigned ox = (c >> 2) & 1, oy = (c >> 1) & 1, oz = c & 1;
        hh[c] = ((cx + ox) ^ ((cy + oy) * 2654435761u) ^ ((cz + oz) * 805459861u)) & (TSZ - 1u);
    }

    unsigned e[8];
    if (l >= 4) {
#pragma unroll
        for (int c = 0; c < 8; ++c) e[c] = __builtin_nontemporal_load(tl + hh[c]);
    } else {
#pragma unroll
        for (int c = 0; c < 8; ++c) e[c] = tl[hh[c]];
    }

    float a0 = 0.f, a1 = 0.f;
#pragma unroll
    for (int c = 0; c < 8; ++c) {
        const unsigned ox = (c >> 2) & 1, oy = (c >> 1) & 1, oz = c & 1;
        const float w = (ox ? fx : 1.f - fx) * (oy ? fy : 1.f - fy) * (oz ? fz : 1.f - fz);
        a0 = fmaf(w, bflo(e[c]), a0);
        a1 = fmaf(w, bfhi(e[c]), a1);
    }
    fws[(size_t)l * (size_t)n + (size_t)idx] =
        ((unsigned)f2bf(a1) << 16) | (unsigned)f2bf(a0);
}

// ---------------- Kernel 2: MFMA MLP (unchanged from R3) -------------------
__global__ __launch_bounds__(256) void ngp_mfma_mlp_kernel(
    const unsigned int* __restrict__ fws,
    const unsigned short* __restrict__ W1t, const float* __restrict__ b1,
    const unsigned short* __restrict__ W2t, const float* __restrict__ b2,
    const float* __restrict__ W3, const float* __restrict__ b3,
    float* __restrict__ out, int n)
{
    __shared__ unsigned short h1_lds[4][64 * WIDTH];  // 4 waves x 8KB
    const int lane = threadIdx.x & 63;
    const int wid  = threadIdx.x >> 6;
    const int wbase = (blockIdx.x * 4 + wid) * 64;
    if (wbase >= n) return;

    unsigned short* myLds = h1_lds[wid];
    const int col = lane & 15;
    const int q   = lane >> 4;

    FragU B1[4];
#pragma unroll
    for (int nt = 0; nt < 4; ++nt)
        B1[nt].u = *reinterpret_cast<const uint4*>(W1t + ((nt * 16 + col) * 32 + q * 8));
    float b1v[4];
#pragma unroll
    for (int nt = 0; nt < 4; ++nt) b1v[nt] = b1[nt * 16 + col];

#pragma unroll
    for (int mt = 0; mt < 4; ++mt) {
        int p = wbase + mt * 16 + col;
        int pc = p < n ? p : n - 1;
        FragU A;
        A.u.x = fws[(size_t)(q * 4 + 0) * (size_t)n + pc];
        A.u.y = fws[(size_t)(q * 4 + 1) * (size_t)n + pc];
        A.u.z = fws[(size_t)(q * 4 + 2) * (size_t)n + pc];
        A.u.w = fws[(size_t)(q * 4 + 3) * (size_t)n + pc];

        f32x4 acc[4] = {f32x4{0.f,0.f,0.f,0.f}, f32x4{0.f,0.f,0.f,0.f},
                        f32x4{0.f,0.f,0.f,0.f}, f32x4{0.f,0.f,0.f,0.f}};
#pragma unroll
        for (int nt = 0; nt < 4; ++nt)
            acc[nt] = __builtin_amdgcn_mfma_f32_16x16x32_bf16(A.v, B1[nt].v, acc[nt], 0, 0, 0);

#pragma unroll
        for (int nt = 0; nt < 4; ++nt) {
#pragma unroll
            for (int r = 0; r < 4; ++r) {
                float v = acc[nt][r] + b1v[nt];
                v = fmaxf(v, 0.f);
                const int pl = mt * 16 + q * 4 + r;
                const int f  = nt * 16 + col;
                myLds[pl * WIDTH + (f ^ ((pl & 7) << 3))] = f2bf(v);
            }
        }
    }

    FragU B2[4][2];
#pragma unroll
    for (int nt = 0; nt < 4; ++nt)
#pragma unroll
        for (int kt = 0; kt < 2; ++kt)
            B2[nt][kt].u = *reinterpret_cast<const uint4*>(
                W2t + ((nt * 16 + col) * 64 + kt * 32 + q * 8));
    float b2v[4], w3v[4];
#pragma unroll
    for (int nt = 0; nt < 4; ++nt) {
        b2v[nt] = b2[nt * 16 + col];
        w3v[nt] = W3[(nt * 16 + col) * OUTW];
    }
    const float bias3 = b3[0];

#pragma unroll
    for (int mt = 0; mt < 4; ++mt) {
        f32x4 acc[4] = {f32x4{0.f,0.f,0.f,0.f}, f32x4{0.f,0.f,0.f,0.f},
                        f32x4{0.f,0.f,0.f,0.f}, f32x4{0.f,0.f,0.f,0.f}};
#pragma unroll
        for (int kt = 0; kt < 2; ++kt) {
            const int pl = mt * 16 + col;
            const int f0 = kt * 32 + q * 8;
            FragU A2;
            A2.u = *reinterpret_cast<const uint4*>(&myLds[pl * WIDTH + (f0 ^ ((pl & 7) << 3))]);
#pragma unroll
            for (int nt = 0; nt < 4; ++nt)
                acc[nt] = __builtin_amdgcn_mfma_f32_16x16x32_bf16(A2.v, B2[nt][kt].v, acc[nt], 0, 0, 0);
        }
        float sp0 = 0.f, sp1 = 0.f, sp2 = 0.f, sp3 = 0.f;
#pragma unroll
        for (int r = 0; r < 4; ++r) {
            float s = 0.f;
#pragma unroll
            for (int nt = 0; nt < 4; ++nt) {
                const float h = fmaxf(acc[nt][r] + b2v[nt], 0.f);
                s = fmaf(h, w3v[nt], s);
            }
            s += __shfl_xor(s, 1);
            s += __shfl_xor(s, 2);
            s += __shfl_xor(s, 4);
            s += __shfl_xor(s, 8);
            const float z0 = s + bias3;
            const float d = (z0 > 0.f) ? (z0 + log1pf(expf(-z0))) : log1pf(expf(z0));
            if (r == 0) sp0 = d; else if (r == 1) sp1 = d; else if (r == 2) sp2 = d; else sp3 = d;
        }
        if (col < 4) {
            const float selv = (col == 0) ? sp0 : (col == 1) ? sp1 : (col == 2) ? sp2 : sp3;
            const int p = wbase + mt * 16 + q * 4 + col;
            if (p < n) out[p] = selv;
        }
    }
}

// ---------------- Fallback: proven fused kernel (R1) ----------------
__global__ __launch_bounds__(256) void ngp_fused_kernel(
    const float* __restrict__ xyz,
    const float* __restrict__ bb,
    const float* __restrict__ table,
    const float* __restrict__ W1, const float* __restrict__ b1,
    const float* __restrict__ W2, const float* __restrict__ b2,
    const float* __restrict__ W3, const float* __restrict__ b3,
    const int* __restrict__ resolutions,
    float* __restrict__ out, int n)
{
    const int idx = blockIdx.x * blockDim.x + threadIdx.x;
    if (idx >= n) return;

    const float bx0 = bb[0], by0 = bb[1], bz0 = bb[2];
    const float bx1 = bb[3], by1 = bb[4], bz1 = bb[5];
    const float x = (xyz[idx * 3 + 0] - bx0) / (bx1 - bx0);
    const float y = (xyz[idx * 3 + 1] - by0) / (by1 - by0);
    const float z = (xyz[idx * 3 + 2] - bz0) / (bz1 - bz0);

    float feats[NL * NF];
#pragma unroll
    for (int l = 0; l < NL; ++l) {
        const float res = (float)resolutions[l];
        const float xs = x * res, ys = y * res, zs = z * res;
        const float xf = floorf(xs), yf = floorf(ys), zf = floorf(zs);
        const float fx = xs - xf, fy = ys - yf, fz = zs - zf;
        const unsigned cx = (unsigned)(int)xf;
        const unsigned cy = (unsigned)(int)yf;
        const unsigned cz = (unsigned)(int)zf;
        const float* tl = table + (size_t)l * (size_t)TSZ * NF;
        float a0 = 0.f, a1 = 0.f;
#pragma unroll
        for (int c = 0; c < 8; ++c) {
            const unsigned ox = (c >> 2) & 1, oy = (c >> 1) & 1, oz = c & 1;
            unsigned h = (cx + ox) ^ ((cy + oy) * 2654435761u) ^ ((cz + oz) * 805459861u);
            h &= (TSZ - 1u);
            const float2 f = *reinterpret_cast<const float2*>(tl + (size_t)h * 2u);
            const float w = (ox ? fx : 1.f - fx) * (oy ? fy : 1.f - fy) * (oz ? fz : 1.f - fz);
            a0 = fmaf(w, f.x, a0);
            a1 = fmaf(w, f.y, a1);
        }
        feats[2 * l]     = a0;
        feats[2 * l + 1] = a1;
    }

    float h1[WIDTH];
#pragma unroll
    for (int j = 0; j < WIDTH; ++j) h1[j] = b1[j];
#pragma unroll
    for (int i = 0; i < NL * NF; ++i) {
        const float v = feats[i];
#pragma unroll
        for (int j = 0; j < WIDTH; ++j) h1[j] = fmaf(v, W1[i * WIDTH + j], h1[j]);
    }
#pragma unroll
    for (int j = 0; j < WIDTH; ++j) h1[j] = fmaxf(h1[j], 0.f);

    float z0 = b3[0];
#pragma unroll 4
    for (int j = 0; j < WIDTH; ++j) {
        float acc = b2[j];
#pragma unroll
        for (int i = 0; i < WIDTH; ++i) acc = fmaf(h1[i], W2[i * WIDTH + j], acc);
        acc = fmaxf(acc, 0.f);
        z0 = fmaf(acc, W3[j * OUTW + 0], z0);
    }

    const float d = (z0 > 0.f) ? (z0 + log1pf(expf(-z0))) : log1pf(expf(z0));
    out[idx] = d;
}

extern "C" void kernel_launch(void* const* d_in, const int* in_sizes, int n_in,
                              void* d_out, int out_size, void* d_ws, size_t ws_size,
                              hipStream_t stream) {
    const float* xyz   = (const float*)d_in[0];
    const float* bb    = (const float*)d_in[1];
    const float* table = (const float*)d_in[2];
    const float* W1    = (const float*)d_in[3];
    const float* b1    = (const float*)d_in[4];
    const float* W2    = (const float*)d_in[5];
    const float* b2    = (const float*)d_in[6];
    const float* W3    = (const float*)d_in[7];
    const float* b3    = (const float*)d_in[8];
    const int*   res   = (const int*)d_in[9];
    float* out = (float*)d_out;
    const int n = out_size;

    const int block = 256;
    const int pblocks = (n + block - 1) / block;

    const size_t fsz  = (size_t)NL * (size_t)n * sizeof(unsigned int);   // 64 MB
    const size_t tbsz = (size_t)NL * (size_t)TSZ * sizeof(unsigned int); // 33.5 MB
    const size_t need = fsz + tbsz + (32 * 64 + 64 * 64) * sizeof(unsigned short) + 256;

    if (ws_size >= need) {
        unsigned int*   fws   = (unsigned int*)d_ws;
        unsigned int*   tb_bf = (unsigned int*)((char*)d_ws + fsz);
        unsigned short* W1t   = (unsigned short*)((char*)d_ws + fsz + tbsz);
        unsigned short* W2t   = W1t + 32 * 64;

        const int tentries = NL * (int)TSZ;
        ngp_prep_table_kernel<<<(tentries + 255) / 256, 256, 0, stream>>>(table, tb_bf);
        ngp_prep_w_kernel<<<24, 256, 0, stream>>>(W1, W2, W1t, W2t);
        dim3 egrid(pblocks, NL);
        ngp_encode_kernel<<<egrid, block, 0, stream>>>(xyz, bb, tb_bf, res, fws, n);
        const int nwaves  = (n + 63) / 64;
        const int mblocks = (nwaves + 3) / 4;
        ngp_mfma_mlp_kernel<<<mblocks, block, 0, stream>>>(fws, W1t, b1, W2t, b2, W3, b3, out, n);
    } else {
        ngp_fused_kernel<<<pblocks, block, 0, stream>>>(xyz, bb, table, W1, b1, W2, b2,
                                                        W3, b3, res, out, n);
    }
}

// Round 6
// 375.053 us; speedup vs baseline: 2.1334x; 1.5131x over previous
//
#include <hip/hip_runtime.h>
#include <math.h>

#define NL 16
#define NF 2
#define LOG2_T 19
#define TSZ (1u << LOG2_T)
#define WIDTH 64
#define OUTW 16

typedef short bf16x8 __attribute__((ext_vector_type(8)));
typedef float f32x4 __attribute__((ext_vector_type(4)));

union FragU { uint4 u; bf16x8 v; };

__device__ __forceinline__ unsigned short f2bf(float f) {
    unsigned u = __builtin_bit_cast(unsigned, f);
    unsigned r = u + 0x7fffu + ((u >> 16) & 1u);
    return (unsigned short)(r >> 16);
}
__device__ __forceinline__ float bflo(unsigned u) {
    return __builtin_bit_cast(float, u << 16);
}
__device__ __forceinline__ float bfhi(unsigned u) {
    return __builtin_bit_cast(float, u & 0xffff0000u);
}

// ---------------- Kernel 0a: table f32 -> packed bf16x2 -------------------
__global__ __launch_bounds__(256) void ngp_prep_table_kernel(
    const float* __restrict__ table, unsigned int* __restrict__ tb_bf)
{
    const int i = blockIdx.x * blockDim.x + threadIdx.x;
    if (i >= NL * (int)TSZ) return;
    const float2 e = *reinterpret_cast<const float2*>(table + (size_t)i * 2u);
    tb_bf[i] = ((unsigned)f2bf(e.y) << 16) | (unsigned)f2bf(e.x);
}

// ---------------- Kernel 0b: weight prep (f32 -> bf16, transposed [n][k]) --
__global__ __launch_bounds__(256) void ngp_prep_w_kernel(
    const float* __restrict__ W1, const float* __restrict__ W2,
    unsigned short* __restrict__ W1t, unsigned short* __restrict__ W2t)
{
    const int i = blockIdx.x * blockDim.x + threadIdx.x;
    if (i < 32 * 64) {                       // W1t[n][k], n=64, k=32
        const int nn = i >> 5, k = i & 31;
        W1t[i] = f2bf(W1[k * 64 + nn]);
    } else if (i < 32 * 64 + 64 * 64) {      // W2t[n][k], n=64, k=64
        const int j = i - 32 * 64;
        const int nn = j >> 6, k = j & 63;
        W2t[j] = f2bf(W2[k * 64 + nn]);
    }
}

// ---------------- Kernel 1: encode with x-corner-pair merged gathers -------
// PRIMES[0]==1 -> for the two x-corners: indices are {H, H^1} (an aligned
// 8B pair in the packed bf16 table). One 64-bit gather serves both
// x-corners -> 4 gathers/level instead of 8.
__global__ __launch_bounds__(256) void ngp_encode_kernel(
    const float* __restrict__ xyz,
    const float* __restrict__ bb,
    const unsigned int* __restrict__ tb_bf,
    const int* __restrict__ resolutions,
    unsigned int* __restrict__ fws, int n)
{
    const int l = blockIdx.y;
    const int idx = blockIdx.x * blockDim.x + threadIdx.x;
    if (idx >= n) return;

    const float bx0 = bb[0], by0 = bb[1], bz0 = bb[2];
    const float bx1 = bb[3], by1 = bb[4], bz1 = bb[5];
    const float x = (xyz[idx * 3 + 0] - bx0) / (bx1 - bx0);
    const float y = (xyz[idx * 3 + 1] - by0) / (by1 - by0);
    const float z = (xyz[idx * 3 + 2] - bz0) / (bz1 - bz0);

    const float res = (float)resolutions[l];
    const float xs = x * res, ys = y * res, zs = z * res;
    const float xf = floorf(xs), yf = floorf(ys), zf = floorf(zs);
    const float fx = xs - xf, fy = ys - yf, fz = zs - zf;
    const unsigned cx = (unsigned)(int)xf;
    const unsigned cy = (unsigned)(int)yf;
    const unsigned cz = (unsigned)(int)zf;
    const unsigned int* tl = tb_bf + (size_t)l * (size_t)TSZ;

    // 4 (y,z) combos; each 64-bit gather covers both x-corners.
    unsigned H[4];
#pragma unroll
    for (int c = 0; c < 4; ++c) {
        const unsigned oy = (c >> 1) & 1, oz = c & 1;
        H[c] = (cx ^ ((cy + oy) * 2654435761u) ^ ((cz + oz) * 805459861u)) & (TSZ - 1u);
    }

    unsigned long long pe[4];
    if (l >= 4) {
#pragma unroll
        for (int c = 0; c < 4; ++c)
            pe[c] = __builtin_nontemporal_load(
                reinterpret_cast<const unsigned long long*>(tl + (H[c] & ~1u)));
    } else {
#pragma unroll
        for (int c = 0; c < 4; ++c)
            pe[c] = *reinterpret_cast<const unsigned long long*>(tl + (H[c] & ~1u));
    }

    float a0 = 0.f, a1 = 0.f;
#pragma unroll
    for (int c = 0; c < 4; ++c) {
        const unsigned oy = (c >> 1) & 1, oz = c & 1;
        const unsigned lo = (unsigned)pe[c];          // entry at even index
        const unsigned hi = (unsigned)(pe[c] >> 32);  // entry at odd index
        // index H[c] is corner cx; H[c]^1 is corner cx+1
        const unsigned odd = H[c] & 1u;
        const unsigned e_lo = odd ? hi : lo;   // corner cx
        const unsigned e_hi = odd ? lo : hi;   // corner cx+1
        const float wyz = (oy ? fy : 1.f - fy) * (oz ? fz : 1.f - fz);
        // x-lerp then accumulate
        const float v0l = bflo(e_lo), v0h = bflo(e_hi);
        const float v1l = bfhi(e_lo), v1h = bfhi(e_hi);
        a0 = fmaf(wyz, fmaf(fx, v0h - v0l, v0l), a0);
        a1 = fmaf(wyz, fmaf(fx, v1h - v1l, v1l), a1);
    }
    fws[(size_t)l * (size_t)n + (size_t)idx] =
        ((unsigned)f2bf(a1) << 16) | (unsigned)f2bf(a0);
}

// ---------------- Kernel 2: MFMA MLP (unchanged) ---------------------------
__global__ __launch_bounds__(256) void ngp_mfma_mlp_kernel(
    const unsigned int* __restrict__ fws,
    const unsigned short* __restrict__ W1t, const float* __restrict__ b1,
    const unsigned short* __restrict__ W2t, const float* __restrict__ b2,
    const float* __restrict__ W3, const float* __restrict__ b3,
    float* __restrict__ out, int n)
{
    __shared__ unsigned short h1_lds[4][64 * WIDTH];
    const int lane = threadIdx.x & 63;
    const int wid  = threadIdx.x >> 6;
    const int wbase = (blockIdx.x * 4 + wid) * 64;
    if (wbase >= n) return;

    unsigned short* myLds = h1_lds[wid];
    const int col = lane & 15;
    const int q   = lane >> 4;

    FragU B1[4];
#pragma unroll
    for (int nt = 0; nt < 4; ++nt)
        B1[nt].u = *reinterpret_cast<const uint4*>(W1t + ((nt * 16 + col) * 32 + q * 8));
    float b1v[4];
#pragma unroll
    for (int nt = 0; nt < 4; ++nt) b1v[nt] = b1[nt * 16 + col];

#pragma unroll
    for (int mt = 0; mt < 4; ++mt) {
        int p = wbase + mt * 16 + col;
        int pc = p < n ? p : n - 1;
        FragU A;
        A.u.x = fws[(size_t)(q * 4 + 0) * (size_t)n + pc];
        A.u.y = fws[(size_t)(q * 4 + 1) * (size_t)n + pc];
        A.u.z = fws[(size_t)(q * 4 + 2) * (size_t)n + pc];
        A.u.w = fws[(size_t)(q * 4 + 3) * (size_t)n + pc];

        f32x4 acc[4] = {f32x4{0.f,0.f,0.f,0.f}, f32x4{0.f,0.f,0.f,0.f},
                        f32x4{0.f,0.f,0.f,0.f}, f32x4{0.f,0.f,0.f,0.f}};
#pragma unroll
        for (int nt = 0; nt < 4; ++nt)
            acc[nt] = __builtin_amdgcn_mfma_f32_16x16x32_bf16(A.v, B1[nt].v, acc[nt], 0, 0, 0);

#pragma unroll
        for (int nt = 0; nt < 4; ++nt) {
#pragma unroll
            for (int r = 0; r < 4; ++r) {
                float v = acc[nt][r] + b1v[nt];
                v = fmaxf(v, 0.f);
                const int pl = mt * 16 + q * 4 + r;
                const int f  = nt * 16 + col;
                myLds[pl * WIDTH + (f ^ ((pl & 7) << 3))] = f2bf(v);
            }
        }
    }

    FragU B2[4][2];
#pragma unroll
    for (int nt = 0; nt < 4; ++nt)
#pragma unroll
        for (int kt = 0; kt < 2; ++kt)
            B2[nt][kt].u = *reinterpret_cast<const uint4*>(
                W2t + ((nt * 16 + col) * 64 + kt * 32 + q * 8));
    float b2v[4], w3v[4];
#pragma unroll
    for (int nt = 0; nt < 4; ++nt) {
        b2v[nt] = b2[nt * 16 + col];
        w3v[nt] = W3[(nt * 16 + col) * OUTW];
    }
    const float bias3 = b3[0];

#pragma unroll
    for (int mt = 0; mt < 4; ++mt) {
        f32x4 acc[4] = {f32x4{0.f,0.f,0.f,0.f}, f32x4{0.f,0.f,0.f,0.f},
                        f32x4{0.f,0.f,0.f,0.f}, f32x4{0.f,0.f,0.f,0.f}};
#pragma unroll
        for (int kt = 0; kt < 2; ++kt) {
            const int pl = mt * 16 + col;
            const int f0 = kt * 32 + q * 8;
            FragU A2;
            A2.u = *reinterpret_cast<const uint4*>(&myLds[pl * WIDTH + (f0 ^ ((pl & 7) << 3))]);
#pragma unroll
            for (int nt = 0; nt < 4; ++nt)
                acc[nt] = __builtin_amdgcn_mfma_f32_16x16x32_bf16(A2.v, B2[nt][kt].v, acc[nt], 0, 0, 0);
        }
        float sp0 = 0.f, sp1 = 0.f, sp2 = 0.f, sp3 = 0.f;
#pragma unroll
        for (int r = 0; r < 4; ++r) {
            float s = 0.f;
#pragma unroll
            for (int nt = 0; nt < 4; ++nt) {
                const float h = fmaxf(acc[nt][r] + b2v[nt], 0.f);
                s = fmaf(h, w3v[nt], s);
            }
            s += __shfl_xor(s, 1);
            s += __shfl_xor(s, 2);
            s += __shfl_xor(s, 4);
            s += __shfl_xor(s, 8);
            const float z0 = s + bias3;
            const float d = (z0 > 0.f) ? (z0 + log1pf(expf(-z0))) : log1pf(expf(z0));
            if (r == 0) sp0 = d; else if (r == 1) sp1 = d; else if (r == 2) sp2 = d; else sp3 = d;
        }
        if (col < 4) {
            const float selv = (col == 0) ? sp0 : (col == 1) ? sp1 : (col == 2) ? sp2 : sp3;
            const int p = wbase + mt * 16 + q * 4 + col;
            if (p < n) out[p] = selv;
        }
    }
}

// ---------------- Fallback: proven fused kernel (R1) ----------------
__global__ __launch_bounds__(256) void ngp_fused_kernel(
    const float* __restrict__ xyz,
    const float* __restrict__ bb,
    const float* __restrict__ table,
    const float* __restrict__ W1, const float* __restrict__ b1,
    const float* __restrict__ W2, const float* __restrict__ b2,
    const float* __restrict__ W3, const float* __restrict__ b3,
    const int* __restrict__ resolutions,
    float* __restrict__ out, int n)
{
    const int idx = blockIdx.x * blockDim.x + threadIdx.x;
    if (idx >= n) return;

    const float bx0 = bb[0], by0 = bb[1], bz0 = bb[2];
    const float bx1 = bb[3], by1 = bb[4], bz1 = bb[5];
    const float x = (xyz[idx * 3 + 0] - bx0) / (bx1 - bx0);
    const float y = (xyz[idx * 3 + 1] - by0) / (by1 - by0);
    const float z = (xyz[idx * 3 + 2] - bz0) / (bz1 - bz0);

    float feats[NL * NF];
#pragma unroll
    for (int l = 0; l < NL; ++l) {
        const float res = (float)resolutions[l];
        const float xs = x * res, ys = y * res, zs = z * res;
        const float xf = floorf(xs), yf = floorf(ys), zf = floorf(zs);
        const float fx = xs - xf, fy = ys - yf, fz = zs - zf;
        const unsigned cx = (unsigned)(int)xf;
        const unsigned cy = (unsigned)(int)yf;
        const unsigned cz = (unsigned)(int)zf;
        const float* tl = table + (size_t)l * (size_t)TSZ * NF;
        float a0 = 0.f, a1 = 0.f;
#pragma unroll
        for (int c = 0; c < 8; ++c) {
            const unsigned ox = (c >> 2) & 1, oy = (c >> 1) & 1, oz = c & 1;
            unsigned h = (cx + ox) ^ ((cy + oy) * 2654435761u) ^ ((cz + oz) * 805459861u);
            h &= (TSZ - 1u);
            const float2 f = *reinterpret_cast<const float2*>(tl + (size_t)h * 2u);
            const float w = (ox ? fx : 1.f - fx) * (oy ? fy : 1.f - fy) * (oz ? fz : 1.f - fz);
            a0 = fmaf(w, f.x, a0);
            a1 = fmaf(w, f.y, a1);
        }
        feats[2 * l]     = a0;
        feats[2 * l + 1] = a1;
    }

    float h1[WIDTH];
#pragma unroll
    for (int j = 0; j < WIDTH; ++j) h1[j] = b1[j];
#pragma unroll
    for (int i = 0; i < NL * NF; ++i) {
        const float v = feats[i];
#pragma unroll
        for (int j = 0; j < WIDTH; ++j) h1[j] = fmaf(v, W1[i * WIDTH + j], h1[j]);
    }
#pragma unroll
    for (int j = 0; j < WIDTH; ++j) h1[j] = fmaxf(h1[j], 0.f);

    float z0 = b3[0];
#pragma unroll 4
    for (int j = 0; j < WIDTH; ++j) {
        float acc = b2[j];
#pragma unroll
        for (int i = 0; i < WIDTH; ++i) acc = fmaf(h1[i], W2[i * WIDTH + j], acc);
        acc = fmaxf(acc, 0.f);
        z0 = fmaf(acc, W3[j * OUTW + 0], z0);
    }

    const float d = (z0 > 0.f) ? (z0 + log1pf(expf(-z0))) : log1pf(expf(z0));
    out[idx] = d;
}

extern "C" void kernel_launch(void* const* d_in, const int* in_sizes, int n_in,
                              void* d_out, int out_size, void* d_ws, size_t ws_size,
                              hipStream_t stream) {
    const float* xyz   = (const float*)d_in[0];
    const float* bb    = (const float*)d_in[1];
    const float* table = (const float*)d_in[2];
    const float* W1    = (const float*)d_in[3];
    const float* b1    = (const float*)d_in[4];
    const float* W2    = (const float*)d_in[5];
    const float* b2    = (const float*)d_in[6];
    const float* W3    = (const float*)d_in[7];
    const float* b3    = (const float*)d_in[8];
    const int*   res   = (const int*)d_in[9];
    float* out = (float*)d_out;
    const int n = out_size;

    const int block = 256;
    const int pblocks = (n + block - 1) / block;

    const size_t fsz  = (size_t)NL * (size_t)n * sizeof(unsigned int);   // 64 MB
    const size_t tbsz = (size_t)NL * (size_t)TSZ * sizeof(unsigned int); // 33.5 MB
    const size_t need = fsz + tbsz + (32 * 64 + 64 * 64) * sizeof(unsigned short) + 256;

    if (ws_size >= need) {
        unsigned int*   fws   = (unsigned int*)d_ws;
        unsigned int*   tb_bf = (unsigned int*)((char*)d_ws + fsz);
        unsigned short* W1t   = (unsigned short*)((char*)d_ws + fsz + tbsz);
        unsigned short* W2t   = W1t + 32 * 64;

        const int tentries = NL * (int)TSZ;
        ngp_prep_table_kernel<<<(tentries + 255) / 256, 256, 0, stream>>>(table, tb_bf);
        ngp_prep_w_kernel<<<24, 256, 0, stream>>>(W1, W2, W1t, W2t);
        dim3 egrid(pblocks, NL);
        ngp_encode_kernel<<<egrid, block, 0, stream>>>(xyz, bb, tb_bf, res, fws, n);
        const int nwaves  = (n + 63) / 64;
        const int mblocks = (nwaves + 3) / 4;
        ngp_mfma_mlp_kernel<<<mblocks, block, 0, stream>>>(fws, W1t, b1, W2t, b2, W3, b3, out, n);
    } else {
        ngp_fused_kernel<<<pblocks, block, 0, stream>>>(xyz, bb, table, W1, b1, W2, b2,
                                                        W3, b3, res, out, n);
    }
}